// Round 1
// baseline (1723.088 us; speedup 1.0000x reference)
//
#include <hip/hip_runtime.h>
#include <math.h>

#define NU_F 0.0031830988618379067f

__device__ __forceinline__ float fast_tanh(float z) {
    // tanh(z) = 1 - 2/(e^{2z}+1); saturates correctly for |z| large.
    float e = __expf(2.0f * z);
    return 1.0f - 2.0f / (e + 1.0f);
}

// acc[j] += h * w[j], j=0..3
#define FMA4(A, HS, W)                          \
    A[0] = fmaf((HS), (W).x, A[0]);             \
    A[1] = fmaf((HS), (W).y, A[1]);             \
    A[2] = fmaf((HS), (W).z, A[2]);             \
    A[3] = fmaf((HS), (W).w, A[3]);

// ---------------------------------------------------------------------------
// Derivative kernel: 16 points/block, propagates (v, v_x, v_t, v_xx) jets.
// Thread layout: 32 comp-groups (4 comps each) x 8 point-groups (2 pts each).
// State LDS layout: SS[c][p][s], p-dim padded to 17, s = {v, vx, vt, vxx}.
// ---------------------------------------------------------------------------
#define PD 16
#define PSTR 17

__global__ __launch_bounds__(256, 3)
void pinn_deriv(const float* __restrict__ xf,
                const float* __restrict__ Win,  const float* __restrict__ bin,
                const float* __restrict__ Whid, const float* __restrict__ bhid,
                const float* __restrict__ Wout, const float* __restrict__ bout,
                float* __restrict__ out)
{
    __shared__ __align__(16) float SS[128 * PSTR * 4];
    __shared__ __align__(16) float Wbuf[2][8 * 128];
    __shared__ float xpt[PD * 2];
    __shared__ float dots[4][PD];

    const int tid = threadIdx.x;
    const int p0  = blockIdx.x * PD;

    if (tid < PD * 2) xpt[tid] = xf[p0 * 2 + tid];
    __syncthreads();

    // ---- input layer: z = x*W0 + t*W1 + b; jet seeds ----
    for (int idx = tid; idx < 128 * PD; idx += 256) {
        const int c = idx >> 4;
        const int p = idx & 15;
        const float x = xpt[2 * p], t = xpt[2 * p + 1];
        const float w0 = Win[c], w1 = Win[128 + c];
        const float z = fmaf(x, w0, fmaf(t, w1, bin[c]));
        const float y = fast_tanh(z);
        const float d = 1.0f - y * y;
        float4 st;
        st.x = y;
        st.y = d * w0;
        st.z = d * w1;
        st.w = -2.0f * y * d * w0 * w0;   // z_xx = 0 at input
        *(float4*)&SS[(c * PSTR + p) * 4] = st;
    }
    __syncthreads();

    const int cg = (tid & 31) * 4;        // this thread's 4 output comps
    const int pl = (tid >> 5) * 2;        // this thread's 2 points

    for (int l = 0; l < 7; ++l) {
        const float* Wl = Whid + l * 16384;
        float4 wpre = *(const float4*)(Wl + tid * 4);   // chunk 0 prefetch

        float acc[2][4][4];               // [pt][state][comp j]
        #pragma unroll
        for (int pt = 0; pt < 2; ++pt)
            #pragma unroll
            for (int s = 0; s < 4; ++s)
                #pragma unroll
                for (int j = 0; j < 4; ++j) acc[pt][s][j] = 0.0f;

        for (int ck = 0; ck < 16; ++ck) {
            *(float4*)&Wbuf[ck & 1][tid * 4] = wpre;
            if (ck < 15) wpre = *(const float4*)(Wl + (ck + 1) * 1024 + tid * 4);
            __syncthreads();
            const float* Wc = Wbuf[ck & 1];
            #pragma unroll
            for (int ii = 0; ii < 8; ++ii) {
                const int i = ck * 8 + ii;
                const float4 w  = *(const float4*)&Wc[ii * 128 + cg];
                const float4 h0 = *(const float4*)&SS[(i * PSTR + pl + 0) * 4];
                const float4 h1 = *(const float4*)&SS[(i * PSTR + pl + 1) * 4];
                FMA4(acc[0][0], h0.x, w); FMA4(acc[0][1], h0.y, w);
                FMA4(acc[0][2], h0.z, w); FMA4(acc[0][3], h0.w, w);
                FMA4(acc[1][0], h1.x, w); FMA4(acc[1][1], h1.y, w);
                FMA4(acc[1][2], h1.z, w); FMA4(acc[1][3], h1.w, w);
            }
        }
        __syncthreads();   // all K-loop reads of SS/Wbuf done

        const float4 bv = *(const float4*)(bhid + l * 128 + cg);
        const float bb[4] = {bv.x, bv.y, bv.z, bv.w};
        #pragma unroll
        for (int pt = 0; pt < 2; ++pt) {
            #pragma unroll
            for (int j = 0; j < 4; ++j) {
                const float zv  = acc[pt][0][j] + bb[j];
                const float zx  = acc[pt][1][j];
                const float zt  = acc[pt][2][j];
                const float zxx = acc[pt][3][j];
                const float y = fast_tanh(zv);
                const float d = 1.0f - y * y;
                float4 st;
                st.x = y;
                st.y = d * zx;
                st.z = d * zt;
                st.w = fmaf(d, zxx, -2.0f * y * d * zx * zx);
                *(float4*)&SS[((cg + j) * PSTR + pl + pt) * 4] = st;
            }
        }
        __syncthreads();   // state ready for next layer
    }

    // ---- output layer: 4 dots (u, ux, ut, uxx) per point ----
    if (tid < 64) {
        const int p = tid & 15;
        const int s = tid >> 4;
        float a = 0.0f;
        #pragma unroll 4
        for (int cc = 0; cc < 128; ++cc) {
            const int c = (cc + 2 * p) & 127;   // stagger to spread banks
            a = fmaf(SS[(c * PSTR + p) * 4 + s], Wout[c], a);
        }
        dots[s][p] = a;
    }
    __syncthreads();
    if (tid < PD) {
        const float u   = dots[0][tid] + bout[0];
        const float res = dots[2][tid] + u * dots[1][tid] - NU_F * dots[3][tid];
        out[8192 + p0 + tid] = res;
    }
}

// ---------------------------------------------------------------------------
// Value-only kernel: 32 points/block over the concatenated x0/xb_left/xb_right.
// ---------------------------------------------------------------------------
#define PV 32
#define VSTR 36

__global__ __launch_bounds__(256, 3)
void pinn_value(const float* __restrict__ x0,  const float* __restrict__ xbl,
                const float* __restrict__ xbr,
                const float* __restrict__ Win,  const float* __restrict__ bin,
                const float* __restrict__ Whid, const float* __restrict__ bhid,
                const float* __restrict__ Wout, const float* __restrict__ bout,
                float* __restrict__ out)
{
    __shared__ __align__(16) float SV[128 * VSTR];
    __shared__ __align__(16) float Wbuf[2][8 * 128];
    __shared__ float xpt[PV * 2];

    const int tid = threadIdx.x;
    const int gp0 = blockIdx.x * PV;

    const float* src;
    if (gp0 < 4096)      src = x0  + gp0 * 2;
    else if (gp0 < 6144) src = xbl + (gp0 - 4096) * 2;
    else                 src = xbr + (gp0 - 6144) * 2;

    if (tid < PV * 2) xpt[tid] = src[tid];
    __syncthreads();

    for (int idx = tid; idx < 128 * PV; idx += 256) {
        const int c = idx >> 5;
        const int p = idx & 31;
        const float z = fmaf(xpt[2 * p], Win[c], fmaf(xpt[2 * p + 1], Win[128 + c], bin[c]));
        SV[c * VSTR + p] = fast_tanh(z);
    }
    __syncthreads();

    const int cg = (tid & 31) * 4;
    const int pl = (tid >> 5) * 4;        // 4 points per thread

    for (int l = 0; l < 7; ++l) {
        const float* Wl = Whid + l * 16384;
        float4 wpre = *(const float4*)(Wl + tid * 4);

        float acc[4][4];                  // [pt][comp j]
        #pragma unroll
        for (int pt = 0; pt < 4; ++pt)
            #pragma unroll
            for (int j = 0; j < 4; ++j) acc[pt][j] = 0.0f;

        for (int ck = 0; ck < 16; ++ck) {
            *(float4*)&Wbuf[ck & 1][tid * 4] = wpre;
            if (ck < 15) wpre = *(const float4*)(Wl + (ck + 1) * 1024 + tid * 4);
            __syncthreads();
            const float* Wc = Wbuf[ck & 1];
            #pragma unroll
            for (int ii = 0; ii < 8; ++ii) {
                const float4 w = *(const float4*)&Wc[ii * 128 + cg];
                const float4 h = *(const float4*)&SV[(ck * 8 + ii) * VSTR + pl];
                FMA4(acc[0], h.x, w); FMA4(acc[1], h.y, w);
                FMA4(acc[2], h.z, w); FMA4(acc[3], h.w, w);
            }
        }
        __syncthreads();

        const float4 bv = *(const float4*)(bhid + l * 128 + cg);
        const float bb[4] = {bv.x, bv.y, bv.z, bv.w};
        #pragma unroll
        for (int j = 0; j < 4; ++j) {
            float4 yv;
            yv.x = fast_tanh(acc[0][j] + bb[j]);
            yv.y = fast_tanh(acc[1][j] + bb[j]);
            yv.z = fast_tanh(acc[2][j] + bb[j]);
            yv.w = fast_tanh(acc[3][j] + bb[j]);
            *(float4*)&SV[(cg + j) * VSTR + pl] = yv;
        }
        __syncthreads();
    }

    if (tid < PV) {
        const int p = tid;
        float a = 0.0f;
        #pragma unroll 4
        for (int cc = 0; cc < 128; ++cc) {
            const int c = (cc + 2 * p) & 127;
            a = fmaf(SV[c * VSTR + p], Wout[c], a);
        }
        out[gp0 + p] = a + bout[0];
    }
}

extern "C" void kernel_launch(void* const* d_in, const int* in_sizes, int n_in,
                              void* d_out, int out_size, void* d_ws, size_t ws_size,
                              hipStream_t stream) {
    (void)in_sizes; (void)n_in; (void)d_ws; (void)ws_size; (void)out_size;
    const float* xf   = (const float*)d_in[0];
    const float* x0   = (const float*)d_in[1];
    const float* xbl  = (const float*)d_in[2];
    const float* xbr  = (const float*)d_in[3];
    const float* Win  = (const float*)d_in[4];
    const float* bin  = (const float*)d_in[5];
    const float* Whid = (const float*)d_in[6];
    const float* bhid = (const float*)d_in[7];
    const float* Wout = (const float*)d_in[8];
    const float* bout = (const float*)d_in[9];
    float* out = (float*)d_out;

    hipLaunchKernelGGL(pinn_value, dim3(8192 / PV), dim3(256), 0, stream,
                       x0, xbl, xbr, Win, bin, Whid, bhid, Wout, bout, out);
    hipLaunchKernelGGL(pinn_deriv, dim3(131072 / PD), dim3(256), 0, stream,
                       xf, Win, bin, Whid, bhid, Wout, bout, out);
}

// Round 2
// 492.777 us; speedup vs baseline: 3.4967x; 3.4967x over previous
//
#include <hip/hip_runtime.h>
#include <math.h>

#define NU_F 0.0031830988618379067f

typedef __bf16 bf16x8 __attribute__((ext_vector_type(8)));
typedef float  f32x4  __attribute__((ext_vector_type(4)));

__device__ __forceinline__ float fast_tanh(float z) {
    float e = __expf(2.0f * z);
    return 1.0f - 2.0f / (e + 1.0f);
}

// ---------------------------------------------------------------------------
// Prep: re-arrange W_hid (fp32 [7][128][128], [l][k_in][c_out]) into bf16
// hi/lo MFMA B-fragment order in d_ws:
//   dst = (((l*4 + ks)*8 + nt)*64 + lane)*8 + j
//   lane = q*16 + (c&15), k = ks*32 + q*8 + j, nt = c>>4
// ---------------------------------------------------------------------------
__global__ void prep_wfrag(const float* __restrict__ Whid,
                           __bf16* __restrict__ whf, __bf16* __restrict__ wlf)
{
    int t = blockIdx.x * 256 + threadIdx.x;   // 0 .. 114687
    const int l = t >> 14;
    const int r = t & 16383;
    const int k = r >> 7;
    const int c = r & 127;
    const float v = Whid[t];
    const __bf16 hi = (__bf16)v;
    const __bf16 lo = (__bf16)(v - (float)hi);
    const int ks = k >> 5, q = (k >> 3) & 3, jj = k & 7;
    const int nt = c >> 4, nn = c & 15;
    const int lane = q * 16 + nn;
    const int dst = (((l * 4 + ks) * 8 + nt) * 64 + lane) * 8 + jj;
    whf[dst] = hi;
    wlf[dst] = lo;
}

// ---------------------------------------------------------------------------
// Derivative kernel (MFMA): 16 points/block, jet states (v, vx, vt, vxx).
// H LDS layout: row st = s*16 + p (s-major), 136 bf16 per row, k contiguous.
// GEMM: Z[st][c] = sum_k H[st][k] * W[k][c] via mfma_f32_16x16x32_bf16,
// hi/lo split (3 MFMAs per product). A = H from LDS, B = W frags from ws.
// C/D layout (verified): lane holds rows quad*4+r, col lane&15 -> with
// s-major tiles, one lane's 4 tile-accs hold all 4 states of (p, c).
// ---------------------------------------------------------------------------
#define HROW 136

__global__ __launch_bounds__(256, 4)
void pinn_deriv_mfma(const float* __restrict__ xf,
                     const float* __restrict__ Win,  const float* __restrict__ bin,
                     const float* __restrict__ bhid,
                     const float* __restrict__ Wout, const float* __restrict__ bout,
                     const __bf16* __restrict__ whf, const __bf16* __restrict__ wlf,
                     float* __restrict__ out)
{
    __shared__ __align__(16) __bf16 Hhi[64 * HROW];
    __shared__ __align__(16) __bf16 Hlo[64 * HROW];
    __shared__ float xpt[32];
    __shared__ float pbuf[256];
    __shared__ float dots[64];

    const int tid  = threadIdx.x;
    const int lane = tid & 63;
    const int wv   = tid >> 6;         // wave 0..3 -> Ntiles {2wv, 2wv+1}
    const int lm   = lane & 15;        // A row-local / B col-local
    const int lq   = lane >> 4;        // quad

    if (tid < 32) xpt[tid] = xf[blockIdx.x * 32 + tid];
    __syncthreads();

    // ---- input layer: seed jets, write split H ----
    {
        const int ci = tid & 127;
        const int ph = (tid >> 7) * 8;
        const float w0 = Win[ci], w1 = Win[128 + ci], bb = bin[ci];
        #pragma unroll
        for (int i = 0; i < 8; ++i) {
            const int p = ph + i;
            const float z = fmaf(xpt[2 * p], w0, fmaf(xpt[2 * p + 1], w1, bb));
            const float y = fast_tanh(z);
            const float d = 1.0f - y * y;
            float hs[4];
            hs[0] = y;
            hs[1] = d * w0;
            hs[2] = d * w1;
            hs[3] = -2.0f * y * d * w0 * w0;
            #pragma unroll
            for (int s = 0; s < 4; ++s) {
                const int idx = (s * 16 + p) * HROW + ci;
                const __bf16 h = (__bf16)hs[s];
                Hhi[idx] = h;
                Hlo[idx] = (__bf16)(hs[s] - (float)h);
            }
        }
    }
    __syncthreads();

    // ---- 7 hidden layers ----
    for (int l = 0; l < 7; ++l) {
        f32x4 acc[4][2];
        #pragma unroll
        for (int s = 0; s < 4; ++s)
            #pragma unroll
            for (int j = 0; j < 2; ++j) acc[s][j] = (f32x4){0.f, 0.f, 0.f, 0.f};

        #pragma unroll
        for (int ks = 0; ks < 4; ++ks) {
            const int koff = ks * 32 + lq * 8;
            bf16x8 ah[4], al[4];
            #pragma unroll
            for (int s = 0; s < 4; ++s) {
                ah[s] = *(const bf16x8*)&Hhi[(s * 16 + lm) * HROW + koff];
                al[s] = *(const bf16x8*)&Hlo[(s * 16 + lm) * HROW + koff];
            }
            #pragma unroll
            for (int j = 0; j < 2; ++j) {
                const int nt = wv * 2 + j;
                const int fo = (((l * 4 + ks) * 8 + nt) * 64 + lane) * 8;
                const bf16x8 bh = *(const bf16x8*)(whf + fo);
                const bf16x8 bl = *(const bf16x8*)(wlf + fo);
                #pragma unroll
                for (int s = 0; s < 4; ++s) {
                    acc[s][j] = __builtin_amdgcn_mfma_f32_16x16x32_bf16(ah[s], bh, acc[s][j], 0, 0, 0);
                    acc[s][j] = __builtin_amdgcn_mfma_f32_16x16x32_bf16(ah[s], bl, acc[s][j], 0, 0, 0);
                    acc[s][j] = __builtin_amdgcn_mfma_f32_16x16x32_bf16(al[s], bh, acc[s][j], 0, 0, 0);
                }
            }
        }
        __syncthreads();   // all K-loop reads of H done before in-place overwrite

        // ---- epilogue: jets in-register, split, write next-layer H ----
        #pragma unroll
        for (int j = 0; j < 2; ++j) {
            const int cg = (wv * 2 + j) * 16 + lm;
            const float b = bhid[l * 128 + cg];
            #pragma unroll
            for (int r = 0; r < 4; ++r) {
                const float zv  = acc[0][j][r] + b;
                const float zx  = acc[1][j][r];
                const float zt  = acc[2][j][r];
                const float zxx = acc[3][j][r];
                const float y = fast_tanh(zv);
                const float d = 1.0f - y * y;
                float hs[4];
                hs[0] = y;
                hs[1] = d * zx;
                hs[2] = d * zt;
                hs[3] = fmaf(d, zxx, -2.0f * y * d * zx * zx);
                const int p = lq * 4 + r;
                #pragma unroll
                for (int s = 0; s < 4; ++s) {
                    const int idx = (s * 16 + p) * HROW + cg;
                    const __bf16 h = (__bf16)hs[s];
                    Hhi[idx] = h;
                    Hlo[idx] = (__bf16)(hs[s] - (float)h);
                }
            }
        }
        __syncthreads();   // H ready for next layer
    }

    // ---- output layer: 64 dots (4 states x 16 pts) of length 128 ----
    {
        const int st = tid & 63;
        const int ch = tid >> 6;           // 4 chunks of 32 channels
        float part = 0.0f;
        #pragma unroll
        for (int c8 = 0; c8 < 4; ++c8) {
            const int c0 = ch * 32 + c8 * 8;
            const bf16x8 hv = *(const bf16x8*)&Hhi[st * HROW + c0];
            const bf16x8 lv = *(const bf16x8*)&Hlo[st * HROW + c0];
            #pragma unroll
            for (int jj = 0; jj < 8; ++jj)
                part = fmaf((float)hv[jj] + (float)lv[jj], Wout[c0 + jj], part);
        }
        pbuf[ch * 64 + st] = part;
    }
    __syncthreads();
    if (tid < 64)
        dots[tid] = pbuf[tid] + pbuf[64 + tid] + pbuf[128 + tid] + pbuf[192 + tid];
    __syncthreads();
    if (tid < 16) {
        const float u   = dots[tid] + bout[0];
        const float res = dots[32 + tid] + u * dots[16 + tid] - NU_F * dots[48 + tid];
        out[8192 + blockIdx.x * 16 + tid] = res;
    }
}

// ---------------------------------------------------------------------------
// Value-only kernel (unchanged from round 1): 32 points/block.
// ---------------------------------------------------------------------------
#define FMA4(A, HS, W)                          \
    A[0] = fmaf((HS), (W).x, A[0]);             \
    A[1] = fmaf((HS), (W).y, A[1]);             \
    A[2] = fmaf((HS), (W).z, A[2]);             \
    A[3] = fmaf((HS), (W).w, A[3]);

#define PV 32
#define VSTR 36

__global__ __launch_bounds__(256, 3)
void pinn_value(const float* __restrict__ x0,  const float* __restrict__ xbl,
                const float* __restrict__ xbr,
                const float* __restrict__ Win,  const float* __restrict__ bin,
                const float* __restrict__ Whid, const float* __restrict__ bhid,
                const float* __restrict__ Wout, const float* __restrict__ bout,
                float* __restrict__ out)
{
    __shared__ __align__(16) float SV[128 * VSTR];
    __shared__ __align__(16) float Wbuf[2][8 * 128];
    __shared__ float xpt[PV * 2];

    const int tid = threadIdx.x;
    const int gp0 = blockIdx.x * PV;

    const float* src;
    if (gp0 < 4096)      src = x0  + gp0 * 2;
    else if (gp0 < 6144) src = xbl + (gp0 - 4096) * 2;
    else                 src = xbr + (gp0 - 6144) * 2;

    if (tid < PV * 2) xpt[tid] = src[tid];
    __syncthreads();

    for (int idx = tid; idx < 128 * PV; idx += 256) {
        const int c = idx >> 5;
        const int p = idx & 31;
        const float z = fmaf(xpt[2 * p], Win[c], fmaf(xpt[2 * p + 1], Win[128 + c], bin[c]));
        SV[c * VSTR + p] = fast_tanh(z);
    }
    __syncthreads();

    const int cg = (tid & 31) * 4;
    const int pl = (tid >> 5) * 4;

    for (int l = 0; l < 7; ++l) {
        const float* Wl = Whid + l * 16384;
        float4 wpre = *(const float4*)(Wl + tid * 4);

        float acc[4][4];
        #pragma unroll
        for (int pt = 0; pt < 4; ++pt)
            #pragma unroll
            for (int j = 0; j < 4; ++j) acc[pt][j] = 0.0f;

        for (int ck = 0; ck < 16; ++ck) {
            *(float4*)&Wbuf[ck & 1][tid * 4] = wpre;
            if (ck < 15) wpre = *(const float4*)(Wl + (ck + 1) * 1024 + tid * 4);
            __syncthreads();
            const float* Wc = Wbuf[ck & 1];
            #pragma unroll
            for (int ii = 0; ii < 8; ++ii) {
                const float4 w = *(const float4*)&Wc[ii * 128 + cg];
                const float4 h = *(const float4*)&SV[(ck * 8 + ii) * VSTR + pl];
                FMA4(acc[0], h.x, w); FMA4(acc[1], h.y, w);
                FMA4(acc[2], h.z, w); FMA4(acc[3], h.w, w);
            }
        }
        __syncthreads();

        const float4 bv = *(const float4*)(bhid + l * 128 + cg);
        const float bb[4] = {bv.x, bv.y, bv.z, bv.w};
        #pragma unroll
        for (int j = 0; j < 4; ++j) {
            float4 yv;
            yv.x = fast_tanh(acc[0][j] + bb[j]);
            yv.y = fast_tanh(acc[1][j] + bb[j]);
            yv.z = fast_tanh(acc[2][j] + bb[j]);
            yv.w = fast_tanh(acc[3][j] + bb[j]);
            *(float4*)&SV[(cg + j) * VSTR + pl] = yv;
        }
        __syncthreads();
    }

    if (tid < PV) {
        const int p = tid;
        float a = 0.0f;
        #pragma unroll 4
        for (int cc = 0; cc < 128; ++cc) {
            const int c = (cc + 2 * p) & 127;
            a = fmaf(SV[c * VSTR + p], Wout[c], a);
        }
        out[gp0 + p] = a + bout[0];
    }
}

extern "C" void kernel_launch(void* const* d_in, const int* in_sizes, int n_in,
                              void* d_out, int out_size, void* d_ws, size_t ws_size,
                              hipStream_t stream) {
    (void)in_sizes; (void)n_in; (void)ws_size; (void)out_size;
    const float* xf   = (const float*)d_in[0];
    const float* x0   = (const float*)d_in[1];
    const float* xbl  = (const float*)d_in[2];
    const float* xbr  = (const float*)d_in[3];
    const float* Win  = (const float*)d_in[4];
    const float* bin  = (const float*)d_in[5];
    const float* Whid = (const float*)d_in[6];
    const float* bhid = (const float*)d_in[7];
    const float* Wout = (const float*)d_in[8];
    const float* bout = (const float*)d_in[9];
    float* out = (float*)d_out;

    __bf16* whf = (__bf16*)d_ws;
    __bf16* wlf = whf + 7 * 128 * 128;

    hipLaunchKernelGGL(prep_wfrag, dim3(114688 / 256), dim3(256), 0, stream,
                       Whid, whf, wlf);
    hipLaunchKernelGGL(pinn_value, dim3(8192 / PV), dim3(256), 0, stream,
                       x0, xbl, xbr, Win, bin, Whid, bhid, Wout, bout, out);
    hipLaunchKernelGGL(pinn_deriv_mfma, dim3(131072 / 16), dim3(256), 0, stream,
                       xf, Win, bin, bhid, Wout, bout, whf, wlf, out);
}